// Round 10
// baseline (168.827 us; speedup 1.0000x reference)
//
#include <hip/hip_runtime.h>
#include <stdint.h>

#define NPTS        16384
#define BATCH       8
#define QPB         128                     // queries per block (4 waves * 32)
#define QBLKS       (NPTS / QPB)            // 128
#define CHAM_BLOCKS (BATCH * 2 * QBLKS)     // 2048
#define NOISE_N     (BATCH * NPTS * 3)      // 393216
#define NOISE_V4    (NOISE_N / 4)           // 98304
#define NPTS_TOT    (BATCH * NPTS)          // 131072
#define PACK_BLOCKS (NPTS_TOT / 256)        // 512
#define REF_ITERS   (NPTS * 8 / 1024)       // 128 groups (1 KB of packed refs each)

// workspace layout (bytes)
#define WS_NOISE_PART 0                     // 512 floats
#define WS_CHAM_PART  4096                  // 2048 floats
#define WS_TICKET     12288                 // 1 uint
#define WS_PK_PRED    16384
#define WS_PK_TARG    (WS_PK_PRED + 8 * NPTS_TOT)
#define WS_R_PRED     (WS_PK_TARG + 8 * NPTS_TOT)
#define WS_R_TARG     (WS_R_PRED + 4 * NPTS_TOT)

using halfx4 = __attribute__((ext_vector_type(4))) _Float16;

__device__ __forceinline__ unsigned int f2h(float f) {
  union { _Float16 h; unsigned short s; } v; v.h = (_Float16)f; return v.s;
}
__device__ __forceinline__ float h2f(unsigned short s) {
  union { _Float16 h; unsigned short u; } v; v.u = s; return (float)v.h;
}

// ---- ternary min tree over a pinned 16-reg bank, destructive, 8 x v_min3 ----
#define T_B0(ACC) \
  "v_min3_f32 v32, v32, v33, v34\n\t" \
  "v_min3_f32 v35, v35, v36, v37\n\t" \
  "v_min3_f32 v38, v38, v39, v40\n\t" \
  "v_min3_f32 v41, v41, v42, v43\n\t" \
  "v_min3_f32 v44, v44, v45, v46\n\t" \
  "v_min3_f32 v32, v32, v35, v38\n\t" \
  "v_min3_f32 v41, v41, v44, v47\n\t" \
  "v_min3_f32 " ACC ", " ACC ", v32, v41\n\t"
#define T_B1(ACC) \
  "v_min3_f32 v48, v48, v49, v50\n\t" \
  "v_min3_f32 v51, v51, v52, v53\n\t" \
  "v_min3_f32 v54, v54, v55, v56\n\t" \
  "v_min3_f32 v57, v57, v58, v59\n\t" \
  "v_min3_f32 v60, v60, v61, v62\n\t" \
  "v_min3_f32 v48, v48, v51, v54\n\t" \
  "v_min3_f32 v57, v57, v60, v63\n\t" \
  "v_min3_f32 " ACC ", " ACC ", v48, v57\n\t"

#define CLOB \
  "v16","v17","v18","v19","v20","v21","v22","v23", \
  "v24","v25","v26","v27","v28","v29","v30","v31", \
  "v32","v33","v34","v35","v36","v37","v38","v39", \
  "v40","v41","v42","v43","v44","v45","v46","v47", \
  "v48","v49","v50","v51","v52","v53","v54","v55", \
  "v56","v57","v58","v59","v60","v61","v62","v63"

// One group: 4 MFMA + 4 trees, cross-group pipelined (this blob's first tree
// finishes the PREVIOUS group's bank1). Loads go straight into pinned slot
// regs (no v_mov shuttles, no VGPR addressing). Prefetch distance = 4 groups,
// guarded by vmcnt(3). BASE is an SGPR pair = slab + (group+1)*1024, so
// offset:3072 lands at (group+4)*1024.
#define BLOB(A0, A1, SLOT, BASE)                                          \
  asm volatile(                                                           \
    "s_waitcnt vmcnt(3)\n\t"                                              \
    "v_mfma_f32_32x32x8_f16 v[32:47], " A0 ", %[b0], 0\n\t"               \
    T_B1("%[m3]")                                                         \
    "v_mfma_f32_32x32x8_f16 v[48:63], " A0 ", %[b1], 0\n\t"               \
    "s_nop 0\n\t"                                                         \
    T_B0("%[m0]")                                                         \
    "v_mfma_f32_32x32x8_f16 v[32:47], " A1 ", %[b0], 0\n\t"               \
    "s_nop 0\n\t"                                                         \
    T_B1("%[m1]")                                                         \
    "v_mfma_f32_32x32x8_f16 v[48:63], " A1 ", %[b1], 0\n\t"               \
    "global_load_dwordx4 " SLOT ", %[voff], %[base] offset:3072\n\t"      \
    "s_nop 0\n\t"                                                         \
    T_B0("%[m2]")                                                         \
    : [m0]"+v"(m0), [m1]"+v"(m1), [m2]"+v"(m2), [m3]"+v"(m3)              \
    : [b0]"v"(fb0.v), [b1]"v"(fb1.v), [voff]"v"(voff), [base]"s"(BASE)    \
    : "memory", CLOB)

// ---------------- fused pack (f32 xyz -> f16 {x,y,z,s} + f32 r) + noise L1 ----------------
__global__ void pack_noise_kernel(const float* __restrict__ pred,
                                  const float* __restrict__ targ,
                                  const float4* __restrict__ na,
                                  const float4* __restrict__ nb,
                                  ushort4* __restrict__ pk_pred,
                                  ushort4* __restrict__ pk_targ,
                                  float* __restrict__ r_pred,
                                  float* __restrict__ r_targ,
                                  float* __restrict__ part,
                                  unsigned int* __restrict__ ticket) {
  int i = blockIdx.x * 256 + threadIdx.x;
  if (i == 0) *ticket = 0u;                 // reset chamfer completion counter
  {
    float x = pred[3*i+0], y = pred[3*i+1], z = pred[3*i+2];
    float s = __builtin_fmaf(x, x, __builtin_fmaf(y, y, z*z));
    pk_pred[i] = make_ushort4((unsigned short)f2h(x), (unsigned short)f2h(y),
                              (unsigned short)f2h(z), (unsigned short)f2h(s));
    r_pred[i] = s;
  }
  {
    float x = targ[3*i+0], y = targ[3*i+1], z = targ[3*i+2];
    float s = __builtin_fmaf(x, x, __builtin_fmaf(y, y, z*z));
    pk_targ[i] = make_ushort4((unsigned short)f2h(x), (unsigned short)f2h(y),
                              (unsigned short)f2h(z), (unsigned short)f2h(s));
    r_targ[i] = s;
  }
  // noise L1 over float4-packed elements (98304 of them < 131072 threads)
  float sn = 0.f;
  if (i < NOISE_V4) {
    float4 pa = na[i], pb = nb[i];
    sn = fabsf(pa.x-pb.x) + fabsf(pa.y-pb.y) + fabsf(pa.z-pb.z) + fabsf(pa.w-pb.w);
  }
  for (int o = 1; o < 64; o <<= 1) sn += __shfl_xor(sn, o);
  __shared__ float ws4[4];
  int lane = threadIdx.x & 63, wv = threadIdx.x >> 6;
  if (lane == 0) ws4[wv] = sn;
  __syncthreads();
  if (threadIdx.x == 0) part[blockIdx.x] = ws4[0] + ws4[1] + ws4[2] + ws4[3];
}

// ---------------- chamfer main kernel (+ fused final reduce via ticket) ----------------
// Full-asm inner loop: pinned prefetch slots v[16:31], MFMA banks v[32:63],
// SGPR-base loads, cross-group-pipelined min3 trees. (256,4): 128-reg budget.
__global__ __launch_bounds__(256, 4)
void chamfer_kernel(const ushort4* __restrict__ pk_pred,
                    const ushort4* __restrict__ pk_targ,
                    const float* __restrict__ r_pred,
                    const float* __restrict__ r_targ,
                    float* __restrict__ part,
                    const float* __restrict__ part_noise,
                    unsigned int* __restrict__ ticket,
                    float* __restrict__ out) {
  __shared__ float wsum[4];
  __shared__ float flagv;

  const int tid  = threadIdx.x;
  const int lane = tid & 63;
  const int wv   = tid >> 6;
  const int col  = lane & 31;

  const int blk  = blockIdx.x;
  const int qblk = blk & (QBLKS - 1);
  const int bd   = blk >> 7;
  const int dir  = bd & 1;
  const int b    = bd >> 1;

  const ushort4* qpk = dir ? pk_targ : pk_pred;
  const float*   qr  = dir ? r_targ  : r_pred;
  const ushort4* ref = dir ? pk_pred : pk_targ;
  qpk += b * NPTS; qr += b * NPTS; ref += b * NPTS;

  // ---- B fragments (queries). 32x32x8: B[k][col], lane l holds col=l&31,
  // k = 4*(l>>5)+e. Variant 0 nonzero at k=0..3 (lanes<32 hold the query
  // [-2x,-2y,-2z,1]); variant 1 at k=4..7.
  const int q = qblk * QPB + wv * 32 + col;
  ushort4 qt = qpk[q];
  unsigned int nx = f2h(-2.f * h2f(qt.x));
  unsigned int ny = f2h(-2.f * h2f(qt.y));
  unsigned int nz = f2h(-2.f * h2f(qt.z));
  unsigned int lo = (ny << 16) | nx;
  unsigned int hi = (0x3C00u << 16) | nz;    // [nz, 1.0f16]
  const bool hh = (lane >= 32);

  union BF { halfx4 v; unsigned int u[2]; };
  BF fb0, fb1;
  fb0.u[0] = hh ? 0u : lo; fb0.u[1] = hh ? 0u : hi;
  fb1.u[0] = hh ? lo : 0u; fb1.u[1] = hh ? hi : 0u;

  const unsigned int voff = (unsigned int)(lane * 16);
  const uint64_t ref_u = (uint64_t)(uintptr_t)ref;

  float m0 = 1e30f, m1 = 1e30f, m2 = 1e30f, m3 = 1e30f;

  // prologue: fill the 4 prefetch slots; init bank1 so blob0's m3-tree
  // (previous-group slot) folds harmless +big values.
  asm volatile(
    "global_load_dwordx4 v[16:19], %[voff], %[base] offset:0\n\t"
    "global_load_dwordx4 v[20:23], %[voff], %[base] offset:1024\n\t"
    "global_load_dwordx4 v[24:27], %[voff], %[base] offset:2048\n\t"
    "global_load_dwordx4 v[28:31], %[voff], %[base] offset:3072\n\t"
    "v_mov_b32 v48, 0x7e000000\n\t" "v_mov_b32 v49, 0x7e000000\n\t"
    "v_mov_b32 v50, 0x7e000000\n\t" "v_mov_b32 v51, 0x7e000000\n\t"
    "v_mov_b32 v52, 0x7e000000\n\t" "v_mov_b32 v53, 0x7e000000\n\t"
    "v_mov_b32 v54, 0x7e000000\n\t" "v_mov_b32 v55, 0x7e000000\n\t"
    "v_mov_b32 v56, 0x7e000000\n\t" "v_mov_b32 v57, 0x7e000000\n\t"
    "v_mov_b32 v58, 0x7e000000\n\t" "v_mov_b32 v59, 0x7e000000\n\t"
    "v_mov_b32 v60, 0x7e000000\n\t" "v_mov_b32 v61, 0x7e000000\n\t"
    "v_mov_b32 v62, 0x7e000000\n\t" "v_mov_b32 v63, 0x7e000000"
    :: [voff]"v"(voff), [base]"s"(ref_u) : "memory", CLOB);

  uint64_t bp = ref_u + 1024;   // blob base: slab + (group+1)*1024
  for (int it = 0; it < REF_ITERS; it += 4) {
    BLOB("v[16:17]", "v[18:19]", "v[16:19]", bp);
    BLOB("v[20:21]", "v[22:23]", "v[20:23]", bp + 1024);
    BLOB("v[24:25]", "v[26:27]", "v[24:27]", bp + 2048);
    BLOB("v[28:29]", "v[30:31]", "v[28:31]", bp + 3072);
    bp += 4096;
  }

  // epilogue: drain in-flight (garbage) prefetches before regs are reused,
  // then reduce the last group's bank1.
  asm volatile(
    "s_waitcnt vmcnt(0)\n\t"
    "s_nop 1\n\t"
    T_B1("%[m3]")
    : [m3]"+v"(m3) :: "memory", CLOB);

  float m = fminf(fminf(m0, m1), fminf(m2, m3));

  // lanes l and l^32 cover complementary rows for the same query column
  m = fminf(m, __shfl_xor(m, 32));
  float rq = qr[q];
  float dmin = fmaxf(rq + m, 0.f);
  float v = (lane < 32) ? dmin : 0.f;
  for (int o = 1; o < 32; o <<= 1) v += __shfl_xor(v, o);
  if (lane == 0) wsum[wv] = v;
  __syncthreads();

  if (tid == 0) {
    atomicExch(&part[blk], wsum[0] + wsum[1] + wsum[2] + wsum[3]);
    __threadfence();
    unsigned int t = atomicAdd(ticket, 1u);
    flagv = (t == CHAM_BLOCKS - 1) ? 1.f : 0.f;
  }
  __syncthreads();

  if (flagv != 0.f) {
    // last block: final reduction (replaces final_kernel)
    float s = 0.f;
    for (int i = tid; i < PACK_BLOCKS; i += 256) s += part_noise[i];
    float c = 0.f;
    for (int i = tid; i < CHAM_BLOCKS; i += 256) c += atomicAdd(&part[i], 0.f);
    float acc = s * (1.f / NOISE_N) + 0.1f * c * (1.f / NPTS_TOT);
    for (int o = 1; o < 64; o <<= 1) acc += __shfl_xor(acc, o);
    __syncthreads();
    if (lane == 0) wsum[wv] = acc;
    __syncthreads();
    if (tid == 0) out[0] = wsum[0] + wsum[1] + wsum[2] + wsum[3];
  }
}

extern "C" void kernel_launch(void* const* d_in, const int* in_sizes, int n_in,
                              void* d_out, int out_size, void* d_ws, size_t ws_size,
                              hipStream_t stream) {
  const float* pn = (const float*)d_in[0];
  const float* an = (const float*)d_in[1];
  const float* pp = (const float*)d_in[2];
  const float* tp = (const float*)d_in[3];

  char* ws = (char*)d_ws;
  float*        noise_part = (float*)(ws + WS_NOISE_PART);
  float*        cham_part  = (float*)(ws + WS_CHAM_PART);
  unsigned int* ticket     = (unsigned int*)(ws + WS_TICKET);
  ushort4*      pk_pred    = (ushort4*)(ws + WS_PK_PRED);
  ushort4*      pk_targ    = (ushort4*)(ws + WS_PK_TARG);
  float*        r_pred     = (float*)(ws + WS_R_PRED);
  float*        r_targ     = (float*)(ws + WS_R_TARG);

  pack_noise_kernel<<<PACK_BLOCKS, 256, 0, stream>>>(pp, tp, (const float4*)pn, (const float4*)an,
                                                     pk_pred, pk_targ, r_pred, r_targ,
                                                     noise_part, ticket);
  chamfer_kernel<<<CHAM_BLOCKS, 256, 0, stream>>>(pk_pred, pk_targ, r_pred, r_targ,
                                                  cham_part, noise_part, ticket, (float*)d_out);
}

// Round 11
// 152.590 us; speedup vs baseline: 1.1064x; 1.1064x over previous
//
#include <hip/hip_runtime.h>
#include <stdint.h>

#define NPTS        16384
#define BATCH       8
#define QPB         128                     // queries per block (4 waves * 32)
#define QBLKS       (NPTS / QPB)            // 128
#define CHAM_BLOCKS (BATCH * 2 * QBLKS)     // 2048
#define NOISE_N     (BATCH * NPTS * 3)      // 393216
#define NOISE_V4    (NOISE_N / 4)           // 98304
#define NPTS_TOT    (BATCH * NPTS)          // 131072
#define PACK_BLOCKS (NPTS_TOT / 256)        // 512
#define REF_ITERS   (NPTS * 8 / 1024)       // 128 groups (1 KB of packed refs each)

// workspace layout (bytes)
#define WS_NOISE_PART 0                     // 512 floats
#define WS_CHAM_PART  4096                  // 2048 floats
#define WS_PK_PRED    16384
#define WS_PK_TARG    (WS_PK_PRED + 8 * NPTS_TOT)
#define WS_R_PRED     (WS_PK_TARG + 8 * NPTS_TOT)
#define WS_R_TARG     (WS_R_PRED + 4 * NPTS_TOT)

using halfx4 = __attribute__((ext_vector_type(4))) _Float16;

__device__ __forceinline__ unsigned int f2h(float f) {
  union { _Float16 h; unsigned short s; } v; v.h = (_Float16)f; return v.s;
}
__device__ __forceinline__ float h2f(unsigned short s) {
  union { _Float16 h; unsigned short u; } v; v.u = s; return (float)v.h;
}

// ---- ternary min tree over a pinned 16-reg bank, destructive, 8 x v_min3 ----
#define T_B0(ACC) \
  "v_min3_f32 v32, v32, v33, v34\n\t" \
  "v_min3_f32 v35, v35, v36, v37\n\t" \
  "v_min3_f32 v38, v38, v39, v40\n\t" \
  "v_min3_f32 v41, v41, v42, v43\n\t" \
  "v_min3_f32 v44, v44, v45, v46\n\t" \
  "v_min3_f32 v32, v32, v35, v38\n\t" \
  "v_min3_f32 v41, v41, v44, v47\n\t" \
  "v_min3_f32 " ACC ", " ACC ", v32, v41\n\t"
#define T_B1(ACC) \
  "v_min3_f32 v48, v48, v49, v50\n\t" \
  "v_min3_f32 v51, v51, v52, v53\n\t" \
  "v_min3_f32 v54, v54, v55, v56\n\t" \
  "v_min3_f32 v57, v57, v58, v59\n\t" \
  "v_min3_f32 v60, v60, v61, v62\n\t" \
  "v_min3_f32 v48, v48, v51, v54\n\t" \
  "v_min3_f32 v57, v57, v60, v63\n\t" \
  "v_min3_f32 " ACC ", " ACC ", v48, v57\n\t"

#define CLOB \
  "v16","v17","v18","v19","v20","v21","v22","v23", \
  "v24","v25","v26","v27","v28","v29","v30","v31", \
  "v32","v33","v34","v35","v36","v37","v38","v39", \
  "v40","v41","v42","v43","v44","v45","v46","v47", \
  "v48","v49","v50","v51","v52","v53","v54","v55", \
  "v56","v57","v58","v59","v60","v61","v62","v63"

// One group: 4 MFMA + 4 trees, cross-group pipelined (first tree finishes the
// PREVIOUS group's bank1). Loads go straight into pinned slot regs -- no
// v_mov shuttles, no VGPR address math (SALU base bump). Prefetch distance
// 4 groups, guarded by vmcnt(3). Pinned footprint: v16-v63 (48 regs);
// compiler state in v0-v15 -> fits the 64-reg/wave budget of (256,8).
#define BLOB(A0, A1, SLOT, BASE)                                          \
  asm volatile(                                                           \
    "s_waitcnt vmcnt(3)\n\t"                                              \
    "v_mfma_f32_32x32x8_f16 v[32:47], " A0 ", %[b0], 0\n\t"               \
    T_B1("%[m3]")                                                         \
    "v_mfma_f32_32x32x8_f16 v[48:63], " A0 ", %[b1], 0\n\t"               \
    "s_nop 0\n\t"                                                         \
    T_B0("%[m0]")                                                         \
    "v_mfma_f32_32x32x8_f16 v[32:47], " A1 ", %[b0], 0\n\t"               \
    "s_nop 0\n\t"                                                         \
    T_B1("%[m1]")                                                         \
    "v_mfma_f32_32x32x8_f16 v[48:63], " A1 ", %[b1], 0\n\t"               \
    "global_load_dwordx4 " SLOT ", %[voff], %[base] offset:3072\n\t"      \
    "s_nop 0\n\t"                                                         \
    T_B0("%[m2]")                                                         \
    : [m0]"+v"(m0), [m1]"+v"(m1), [m2]"+v"(m2), [m3]"+v"(m3)              \
    : [b0]"v"(fb0.v), [b1]"v"(fb1.v), [voff]"v"(voff), [base]"s"(BASE)    \
    : "memory", CLOB)

// ---------------- fused pack (f32 xyz -> f16 {x,y,z,s} + f32 r) + noise L1 ----------------
__global__ void pack_noise_kernel(const float* __restrict__ pred,
                                  const float* __restrict__ targ,
                                  const float4* __restrict__ na,
                                  const float4* __restrict__ nb,
                                  ushort4* __restrict__ pk_pred,
                                  ushort4* __restrict__ pk_targ,
                                  float* __restrict__ r_pred,
                                  float* __restrict__ r_targ,
                                  float* __restrict__ part) {
  int i = blockIdx.x * 256 + threadIdx.x;
  {
    float x = pred[3*i+0], y = pred[3*i+1], z = pred[3*i+2];
    float s = __builtin_fmaf(x, x, __builtin_fmaf(y, y, z*z));
    pk_pred[i] = make_ushort4((unsigned short)f2h(x), (unsigned short)f2h(y),
                              (unsigned short)f2h(z), (unsigned short)f2h(s));
    r_pred[i] = s;
  }
  {
    float x = targ[3*i+0], y = targ[3*i+1], z = targ[3*i+2];
    float s = __builtin_fmaf(x, x, __builtin_fmaf(y, y, z*z));
    pk_targ[i] = make_ushort4((unsigned short)f2h(x), (unsigned short)f2h(y),
                              (unsigned short)f2h(z), (unsigned short)f2h(s));
    r_targ[i] = s;
  }
  // noise L1 over float4-packed elements (98304 of them < 131072 threads)
  float sn = 0.f;
  if (i < NOISE_V4) {
    float4 pa = na[i], pb = nb[i];
    sn = fabsf(pa.x-pb.x) + fabsf(pa.y-pb.y) + fabsf(pa.z-pb.z) + fabsf(pa.w-pb.w);
  }
  for (int o = 1; o < 64; o <<= 1) sn += __shfl_xor(sn, o);
  __shared__ float ws4[4];
  int lane = threadIdx.x & 63, wv = threadIdx.x >> 6;
  if (lane == 0) ws4[wv] = sn;
  __syncthreads();
  if (threadIdx.x == 0) part[blockIdx.x] = ws4[0] + ws4[1] + ws4[2] + ws4[3];
}

// ---------------- chamfer main kernel ----------------
// Pinned-asm inner loop (v16-63) AT FULL OCCUPANCY: (256,8) -> 64 regs/wave,
// 8 waves/SIMD. R2-R10 post-mortem: every variant ran at ~4 waves/SIMD and
// stalled ~50% regardless of inner-loop form; this is the untested quadrant
// (low-reg pinned loop x 8 waves). Grid 2048 = exactly 1 residency round.
__global__ __launch_bounds__(256, 8)
void chamfer_kernel(const ushort4* __restrict__ pk_pred,
                    const ushort4* __restrict__ pk_targ,
                    const float* __restrict__ r_pred,
                    const float* __restrict__ r_targ,
                    float* __restrict__ part) {
  __shared__ float wsum[4];

  const int tid  = threadIdx.x;
  const int lane = tid & 63;
  const int wv   = tid >> 6;
  const int col  = lane & 31;

  const int blk  = blockIdx.x;
  const int qblk = blk & (QBLKS - 1);
  const int bd   = blk >> 7;
  const int dir  = bd & 1;
  const int b    = bd >> 1;

  const ushort4* qpk = dir ? pk_targ : pk_pred;
  const float*   qr  = dir ? r_targ  : r_pred;
  const ushort4* ref = dir ? pk_pred : pk_targ;
  qpk += b * NPTS; qr += b * NPTS; ref += b * NPTS;

  // ---- B fragments (queries). 32x32x8: B[k][col], lane l holds col=l&31,
  // k = 4*(l>>5)+e. Variant 0 nonzero at k=0..3 (lanes<32 hold the query
  // [-2x,-2y,-2z,1]); variant 1 at k=4..7.
  const int q = qblk * QPB + wv * 32 + col;
  ushort4 qt = qpk[q];
  unsigned int nx = f2h(-2.f * h2f(qt.x));
  unsigned int ny = f2h(-2.f * h2f(qt.y));
  unsigned int nz = f2h(-2.f * h2f(qt.z));
  unsigned int lo = (ny << 16) | nx;
  unsigned int hi = (0x3C00u << 16) | nz;    // [nz, 1.0f16]
  const bool hh = (lane >= 32);

  union BF { halfx4 v; unsigned int u[2]; };
  BF fb0, fb1;
  fb0.u[0] = hh ? 0u : lo; fb0.u[1] = hh ? 0u : hi;
  fb1.u[0] = hh ? lo : 0u; fb1.u[1] = hh ? hi : 0u;

  const unsigned int voff = (unsigned int)(lane * 16);
  const uint64_t ref_u = (uint64_t)(uintptr_t)ref;

  float m0 = 1e30f, m1 = 1e30f, m2 = 1e30f, m3 = 1e30f;

  // prologue: fill the 4 prefetch slots; init bank1 so blob0's m3-tree
  // (previous-group slot) folds harmless +big values.
  asm volatile(
    "global_load_dwordx4 v[16:19], %[voff], %[base] offset:0\n\t"
    "global_load_dwordx4 v[20:23], %[voff], %[base] offset:1024\n\t"
    "global_load_dwordx4 v[24:27], %[voff], %[base] offset:2048\n\t"
    "global_load_dwordx4 v[28:31], %[voff], %[base] offset:3072\n\t"
    "v_mov_b32 v48, 0x7e000000\n\t" "v_mov_b32 v49, 0x7e000000\n\t"
    "v_mov_b32 v50, 0x7e000000\n\t" "v_mov_b32 v51, 0x7e000000\n\t"
    "v_mov_b32 v52, 0x7e000000\n\t" "v_mov_b32 v53, 0x7e000000\n\t"
    "v_mov_b32 v54, 0x7e000000\n\t" "v_mov_b32 v55, 0x7e000000\n\t"
    "v_mov_b32 v56, 0x7e000000\n\t" "v_mov_b32 v57, 0x7e000000\n\t"
    "v_mov_b32 v58, 0x7e000000\n\t" "v_mov_b32 v59, 0x7e000000\n\t"
    "v_mov_b32 v60, 0x7e000000\n\t" "v_mov_b32 v61, 0x7e000000\n\t"
    "v_mov_b32 v62, 0x7e000000\n\t" "v_mov_b32 v63, 0x7e000000"
    :: [voff]"v"(voff), [base]"s"(ref_u) : "memory", CLOB);

  uint64_t bp = ref_u + 1024;   // blob base: slab + (group+1)*1024
  for (int it = 0; it < REF_ITERS; it += 4) {
    BLOB("v[16:17]", "v[18:19]", "v[16:19]", bp);
    BLOB("v[20:21]", "v[22:23]", "v[20:23]", bp + 1024);
    BLOB("v[24:25]", "v[26:27]", "v[24:27]", bp + 2048);
    BLOB("v[28:29]", "v[30:31]", "v[28:31]", bp + 3072);
    bp += 4096;
  }

  // epilogue: drain in-flight (garbage) prefetches before regs are reused,
  // then reduce the last group's bank1.
  asm volatile(
    "s_waitcnt vmcnt(0)\n\t"
    "s_nop 1\n\t"
    T_B1("%[m3]")
    : [m3]"+v"(m3) :: "memory", CLOB);

  float m = fminf(fminf(m0, m1), fminf(m2, m3));

  // lanes l and l^32 cover complementary rows for the same query column
  m = fminf(m, __shfl_xor(m, 32));
  float rq = qr[q];
  float dmin = fmaxf(rq + m, 0.f);
  float v = (lane < 32) ? dmin : 0.f;
  for (int o = 1; o < 32; o <<= 1) v += __shfl_xor(v, o);
  if (lane == 0) wsum[wv] = v;
  __syncthreads();
  if (tid == 0) part[blockIdx.x] = wsum[0] + wsum[1] + wsum[2] + wsum[3];
}

// ---------------- final reduce ----------------
__global__ void final_kernel(const float* __restrict__ part_noise,
                             const float* __restrict__ part_cham,
                             float* __restrict__ out) {
  __shared__ float red[256];
  float s = 0.f;
  for (int i = threadIdx.x; i < PACK_BLOCKS; i += 256) s += part_noise[i];
  float t = 0.f;
  for (int i = threadIdx.x; i < CHAM_BLOCKS; i += 256) t += part_cham[i];
  red[threadIdx.x] = s; __syncthreads();
  for (int o = 128; o; o >>= 1) { if (threadIdx.x < o) red[threadIdx.x] += red[threadIdx.x + o]; __syncthreads(); }
  float noise_sum = red[0];
  __syncthreads();
  red[threadIdx.x] = t; __syncthreads();
  for (int o = 128; o; o >>= 1) { if (threadIdx.x < o) red[threadIdx.x] += red[threadIdx.x + o]; __syncthreads(); }
  if (threadIdx.x == 0)
    out[0] = noise_sum * (1.f / NOISE_N) + 0.1f * red[0] * (1.f / NPTS_TOT);
}

extern "C" void kernel_launch(void* const* d_in, const int* in_sizes, int n_in,
                              void* d_out, int out_size, void* d_ws, size_t ws_size,
                              hipStream_t stream) {
  const float* pn = (const float*)d_in[0];
  const float* an = (const float*)d_in[1];
  const float* pp = (const float*)d_in[2];
  const float* tp = (const float*)d_in[3];

  char* ws = (char*)d_ws;
  float*   noise_part = (float*)(ws + WS_NOISE_PART);
  float*   cham_part  = (float*)(ws + WS_CHAM_PART);
  ushort4* pk_pred    = (ushort4*)(ws + WS_PK_PRED);
  ushort4* pk_targ    = (ushort4*)(ws + WS_PK_TARG);
  float*   r_pred     = (float*)(ws + WS_R_PRED);
  float*   r_targ     = (float*)(ws + WS_R_TARG);

  pack_noise_kernel<<<PACK_BLOCKS, 256, 0, stream>>>(pp, tp, (const float4*)pn, (const float4*)an,
                                                     pk_pred, pk_targ, r_pred, r_targ, noise_part);
  chamfer_kernel<<<CHAM_BLOCKS, 256, 0, stream>>>(pk_pred, pk_targ, r_pred, r_targ, cham_part);
  final_kernel<<<1, 256, 0, stream>>>(noise_part, cham_part, (float*)d_out);
}

// Round 12
// 150.212 us; speedup vs baseline: 1.1239x; 1.0158x over previous
//
#include <hip/hip_runtime.h>
#include <stdint.h>

#define NPTS        16384
#define BATCH       8
#define QPB         128                     // queries per block (4 waves * 32)
#define QBLKS       (NPTS / QPB)            // 128
#define CHAM_BLOCKS (BATCH * 2 * QBLKS)     // 2048
#define NOISE_N     (BATCH * NPTS * 3)      // 393216
#define NOISE_V4    (NOISE_N / 4)           // 98304
#define NPTS_TOT    (BATCH * NPTS)          // 131072
#define PACK_THREADS 128
#define PACK_BLOCKS  256                    // 32768 threads, 4 points each
#define REF_ITERS   (NPTS * 8 / 1024)       // 128 groups (1 KB of packed refs each)

// workspace layout (bytes)
#define WS_NOISE_PART 0                     // 256 floats
#define WS_CHAM_PART  4096                  // 2048 floats
#define WS_PK_PRED    16384
#define WS_PK_TARG    (WS_PK_PRED + 8 * NPTS_TOT)
#define WS_R_PRED     (WS_PK_TARG + 8 * NPTS_TOT)
#define WS_R_TARG     (WS_R_PRED + 4 * NPTS_TOT)

using halfx4 = __attribute__((ext_vector_type(4))) _Float16;

__device__ __forceinline__ unsigned int f2h(float f) {
  union { _Float16 h; unsigned short s; } v; v.h = (_Float16)f; return v.s;
}
__device__ __forceinline__ float h2f(unsigned short s) {
  union { _Float16 h; unsigned short u; } v; v.u = s; return (float)v.h;
}

// ---- ternary min tree over a pinned 16-reg bank, destructive, 8 x v_min3 ----
#define T_B0(ACC) \
  "v_min3_f32 v32, v32, v33, v34\n\t" \
  "v_min3_f32 v35, v35, v36, v37\n\t" \
  "v_min3_f32 v38, v38, v39, v40\n\t" \
  "v_min3_f32 v41, v41, v42, v43\n\t" \
  "v_min3_f32 v44, v44, v45, v46\n\t" \
  "v_min3_f32 v32, v32, v35, v38\n\t" \
  "v_min3_f32 v41, v41, v44, v47\n\t" \
  "v_min3_f32 " ACC ", " ACC ", v32, v41\n\t"
#define T_B1(ACC) \
  "v_min3_f32 v48, v48, v49, v50\n\t" \
  "v_min3_f32 v51, v51, v52, v53\n\t" \
  "v_min3_f32 v54, v54, v55, v56\n\t" \
  "v_min3_f32 v57, v57, v58, v59\n\t" \
  "v_min3_f32 v60, v60, v61, v62\n\t" \
  "v_min3_f32 v48, v48, v51, v54\n\t" \
  "v_min3_f32 v57, v57, v60, v63\n\t" \
  "v_min3_f32 " ACC ", " ACC ", v48, v57\n\t"

#define CLOB \
  "v16","v17","v18","v19","v20","v21","v22","v23", \
  "v24","v25","v26","v27","v28","v29","v30","v31", \
  "v32","v33","v34","v35","v36","v37","v38","v39", \
  "v40","v41","v42","v43","v44","v45","v46","v47", \
  "v48","v49","v50","v51","v52","v53","v54","v55", \
  "v56","v57","v58","v59","v60","v61","v62","v63"

// One group: 4 MFMA + 4 trees, cross-group pipelined (first tree finishes the
// PREVIOUS group's bank1). Loads go straight into pinned slot regs -- no
// v_mov shuttles, no VGPR address math (SALU base bump). Prefetch distance
// 4 groups, guarded by vmcnt(3). Pinned footprint: v16-v63 (48 regs);
// compiler state in v0-v15 -> fits the 64-reg/wave budget of (256,8).
#define BLOB(A0, A1, SLOT, BASE)                                          \
  asm volatile(                                                           \
    "s_waitcnt vmcnt(3)\n\t"                                              \
    "v_mfma_f32_32x32x8_f16 v[32:47], " A0 ", %[b0], 0\n\t"               \
    T_B1("%[m3]")                                                         \
    "v_mfma_f32_32x32x8_f16 v[48:63], " A0 ", %[b1], 0\n\t"               \
    "s_nop 0\n\t"                                                         \
    T_B0("%[m0]")                                                         \
    "v_mfma_f32_32x32x8_f16 v[32:47], " A1 ", %[b0], 0\n\t"               \
    "s_nop 0\n\t"                                                         \
    T_B1("%[m1]")                                                         \
    "v_mfma_f32_32x32x8_f16 v[48:63], " A1 ", %[b1], 0\n\t"               \
    "global_load_dwordx4 " SLOT ", %[voff], %[base] offset:3072\n\t"      \
    "s_nop 0\n\t"                                                         \
    T_B0("%[m2]")                                                         \
    : [m0]"+v"(m0), [m1]"+v"(m1), [m2]"+v"(m2), [m3]"+v"(m3)              \
    : [b0]"v"(fb0.v), [b1]"v"(fb1.v), [voff]"v"(voff), [base]"s"(BASE)    \
    : "memory", CLOB)

// ---------------- fused pack + noise L1 (fully vectorized, G13) ----------------
// 4 points per thread: 3 x float4 loads per array (48 B, 16B-aligned),
// 2 x uint4 stores for packed f16, 1 x float4 store for r. Noise handled as
// 3 float4 pairs per thread (98304 = 3 * 32768 exactly).
__device__ __forceinline__ uint2 pkpt(float x, float y, float z, float& s) {
  s = __builtin_fmaf(x, x, __builtin_fmaf(y, y, z * z));
  uint2 r;
  r.x = f2h(x) | (f2h(y) << 16);
  r.y = f2h(z) | (f2h(s) << 16);
  return r;
}

__global__ __launch_bounds__(PACK_THREADS)
void pack_noise_kernel(const float4* __restrict__ pred4,
                       const float4* __restrict__ targ4,
                       const float4* __restrict__ na,
                       const float4* __restrict__ nb,
                       uint4* __restrict__ pk_pred,
                       uint4* __restrict__ pk_targ,
                       float4* __restrict__ r_pred,
                       float4* __restrict__ r_targ,
                       float* __restrict__ part) {
  const int t = blockIdx.x * PACK_THREADS + threadIdx.x;   // 0..32767

  {
    float4 a0 = pred4[3*t], a1 = pred4[3*t+1], a2 = pred4[3*t+2];
    float s0, s1, s2, s3;
    uint2 q0 = pkpt(a0.x, a0.y, a0.z, s0);
    uint2 q1 = pkpt(a0.w, a1.x, a1.y, s1);
    uint2 q2 = pkpt(a1.z, a1.w, a2.x, s2);
    uint2 q3 = pkpt(a2.y, a2.z, a2.w, s3);
    pk_pred[2*t]   = make_uint4(q0.x, q0.y, q1.x, q1.y);
    pk_pred[2*t+1] = make_uint4(q2.x, q2.y, q3.x, q3.y);
    r_pred[t] = make_float4(s0, s1, s2, s3);
  }
  {
    float4 a0 = targ4[3*t], a1 = targ4[3*t+1], a2 = targ4[3*t+2];
    float s0, s1, s2, s3;
    uint2 q0 = pkpt(a0.x, a0.y, a0.z, s0);
    uint2 q1 = pkpt(a0.w, a1.x, a1.y, s1);
    uint2 q2 = pkpt(a1.z, a1.w, a2.x, s2);
    uint2 q3 = pkpt(a2.y, a2.z, a2.w, s3);
    pk_targ[2*t]   = make_uint4(q0.x, q0.y, q1.x, q1.y);
    pk_targ[2*t+1] = make_uint4(q2.x, q2.y, q3.x, q3.y);
    r_targ[t] = make_float4(s0, s1, s2, s3);
  }

  // noise L1: exactly 3 float4 pairs per thread
  float sn = 0.f;
#pragma unroll
  for (int k = 0; k < 3; ++k) {
    float4 pa = na[3*t+k], pb = nb[3*t+k];
    sn += fabsf(pa.x-pb.x) + fabsf(pa.y-pb.y) + fabsf(pa.z-pb.z) + fabsf(pa.w-pb.w);
  }
  for (int o = 1; o < 64; o <<= 1) sn += __shfl_xor(sn, o);
  __shared__ float ws2[2];
  int lane = threadIdx.x & 63, wv = threadIdx.x >> 6;
  if (lane == 0) ws2[wv] = sn;
  __syncthreads();
  if (threadIdx.x == 0) part[blockIdx.x] = ws2[0] + ws2[1];
}

// ---------------- chamfer main kernel (UNCHANGED from R11 -- best measured) ----------------
__global__ __launch_bounds__(256, 8)
void chamfer_kernel(const ushort4* __restrict__ pk_pred,
                    const ushort4* __restrict__ pk_targ,
                    const float* __restrict__ r_pred,
                    const float* __restrict__ r_targ,
                    float* __restrict__ part) {
  __shared__ float wsum[4];

  const int tid  = threadIdx.x;
  const int lane = tid & 63;
  const int wv   = tid >> 6;
  const int col  = lane & 31;

  const int blk  = blockIdx.x;
  const int qblk = blk & (QBLKS - 1);
  const int bd   = blk >> 7;
  const int dir  = bd & 1;
  const int b    = bd >> 1;

  const ushort4* qpk = dir ? pk_targ : pk_pred;
  const float*   qr  = dir ? r_targ  : r_pred;
  const ushort4* ref = dir ? pk_pred : pk_targ;
  qpk += b * NPTS; qr += b * NPTS; ref += b * NPTS;

  // ---- B fragments (queries). 32x32x8: B[k][col], lane l holds col=l&31,
  // k = 4*(l>>5)+e. Variant 0 nonzero at k=0..3 (lanes<32 hold the query
  // [-2x,-2y,-2z,1]); variant 1 at k=4..7.
  const int q = qblk * QPB + wv * 32 + col;
  ushort4 qt = qpk[q];
  unsigned int nx = f2h(-2.f * h2f(qt.x));
  unsigned int ny = f2h(-2.f * h2f(qt.y));
  unsigned int nz = f2h(-2.f * h2f(qt.z));
  unsigned int lo = (ny << 16) | nx;
  unsigned int hi = (0x3C00u << 16) | nz;    // [nz, 1.0f16]
  const bool hh = (lane >= 32);

  union BF { halfx4 v; unsigned int u[2]; };
  BF fb0, fb1;
  fb0.u[0] = hh ? 0u : lo; fb0.u[1] = hh ? 0u : hi;
  fb1.u[0] = hh ? lo : 0u; fb1.u[1] = hh ? hi : 0u;

  const unsigned int voff = (unsigned int)(lane * 16);
  const uint64_t ref_u = (uint64_t)(uintptr_t)ref;

  float m0 = 1e30f, m1 = 1e30f, m2 = 1e30f, m3 = 1e30f;

  // prologue: fill the 4 prefetch slots; init bank1 so blob0's m3-tree
  // (previous-group slot) folds harmless +big values.
  asm volatile(
    "global_load_dwordx4 v[16:19], %[voff], %[base] offset:0\n\t"
    "global_load_dwordx4 v[20:23], %[voff], %[base] offset:1024\n\t"
    "global_load_dwordx4 v[24:27], %[voff], %[base] offset:2048\n\t"
    "global_load_dwordx4 v[28:31], %[voff], %[base] offset:3072\n\t"
    "v_mov_b32 v48, 0x7e000000\n\t" "v_mov_b32 v49, 0x7e000000\n\t"
    "v_mov_b32 v50, 0x7e000000\n\t" "v_mov_b32 v51, 0x7e000000\n\t"
    "v_mov_b32 v52, 0x7e000000\n\t" "v_mov_b32 v53, 0x7e000000\n\t"
    "v_mov_b32 v54, 0x7e000000\n\t" "v_mov_b32 v55, 0x7e000000\n\t"
    "v_mov_b32 v56, 0x7e000000\n\t" "v_mov_b32 v57, 0x7e000000\n\t"
    "v_mov_b32 v58, 0x7e000000\n\t" "v_mov_b32 v59, 0x7e000000\n\t"
    "v_mov_b32 v60, 0x7e000000\n\t" "v_mov_b32 v61, 0x7e000000\n\t"
    "v_mov_b32 v62, 0x7e000000\n\t" "v_mov_b32 v63, 0x7e000000"
    :: [voff]"v"(voff), [base]"s"(ref_u) : "memory", CLOB);

  uint64_t bp = ref_u + 1024;   // blob base: slab + (group+1)*1024
  for (int it = 0; it < REF_ITERS; it += 4) {
    BLOB("v[16:17]", "v[18:19]", "v[16:19]", bp);
    BLOB("v[20:21]", "v[22:23]", "v[20:23]", bp + 1024);
    BLOB("v[24:25]", "v[26:27]", "v[24:27]", bp + 2048);
    BLOB("v[28:29]", "v[30:31]", "v[28:31]", bp + 3072);
    bp += 4096;
  }

  // epilogue: drain in-flight (garbage) prefetches before regs are reused,
  // then reduce the last group's bank1.
  asm volatile(
    "s_waitcnt vmcnt(0)\n\t"
    "s_nop 1\n\t"
    T_B1("%[m3]")
    : [m3]"+v"(m3) :: "memory", CLOB);

  float m = fminf(fminf(m0, m1), fminf(m2, m3));

  // lanes l and l^32 cover complementary rows for the same query column
  m = fminf(m, __shfl_xor(m, 32));
  float rq = qr[q];
  float dmin = fmaxf(rq + m, 0.f);
  float v = (lane < 32) ? dmin : 0.f;
  for (int o = 1; o < 32; o <<= 1) v += __shfl_xor(v, o);
  if (lane == 0) wsum[wv] = v;
  __syncthreads();
  if (tid == 0) part[blockIdx.x] = wsum[0] + wsum[1] + wsum[2] + wsum[3];
}

// ---------------- final reduce ----------------
__global__ void final_kernel(const float* __restrict__ part_noise,
                             const float* __restrict__ part_cham,
                             float* __restrict__ out) {
  // 256 threads: noise partial (1 each) + chamfer partials (8 each),
  // pre-weighted so a single reduction suffices.
  float acc = part_noise[threadIdx.x] * (1.f / NOISE_N);
  for (int i = threadIdx.x; i < CHAM_BLOCKS; i += 256)
    acc += part_cham[i] * (0.1f / NPTS_TOT);
  for (int o = 1; o < 64; o <<= 1) acc += __shfl_xor(acc, o);
  __shared__ float ws4[4];
  int lane = threadIdx.x & 63, wv = threadIdx.x >> 6;
  if (lane == 0) ws4[wv] = acc;
  __syncthreads();
  if (threadIdx.x == 0) out[0] = ws4[0] + ws4[1] + ws4[2] + ws4[3];
}

extern "C" void kernel_launch(void* const* d_in, const int* in_sizes, int n_in,
                              void* d_out, int out_size, void* d_ws, size_t ws_size,
                              hipStream_t stream) {
  const float* pn = (const float*)d_in[0];
  const float* an = (const float*)d_in[1];
  const float* pp = (const float*)d_in[2];
  const float* tp = (const float*)d_in[3];

  char* ws = (char*)d_ws;
  float*   noise_part = (float*)(ws + WS_NOISE_PART);
  float*   cham_part  = (float*)(ws + WS_CHAM_PART);
  ushort4* pk_pred    = (ushort4*)(ws + WS_PK_PRED);
  ushort4* pk_targ    = (ushort4*)(ws + WS_PK_TARG);
  float*   r_pred     = (float*)(ws + WS_R_PRED);
  float*   r_targ     = (float*)(ws + WS_R_TARG);

  pack_noise_kernel<<<PACK_BLOCKS, PACK_THREADS, 0, stream>>>(
      (const float4*)pp, (const float4*)tp, (const float4*)pn, (const float4*)an,
      (uint4*)pk_pred, (uint4*)pk_targ, (float4*)r_pred, (float4*)r_targ, noise_part);
  chamfer_kernel<<<CHAM_BLOCKS, 256, 0, stream>>>(pk_pred, pk_targ, r_pred, r_targ, cham_part);
  final_kernel<<<1, 256, 0, stream>>>(noise_part, cham_part, (float*)d_out);
}